// Round 6
// baseline (2355.725 us; speedup 1.0000x reference)
//
#include <hip/hip_runtime.h>
#include <math.h>
#include <float.h>

#define NB 8
#define NC 24
#define NA 96
#define NW 96
#define NF 32
#define NHID 128
#define AW (NA*NW)           // 9216
#define NBC (NB*NC)          // 192
#define NEL ((size_t)NBC*AW) // 1769472

// ---------------------------------------------------------------- stats
__global__ __launch_bounds__(256) void stats_kernel(
    const float* __restrict__ x, const int* __restrict__ rows_len,
    const int* __restrict__ cols_len, float* __restrict__ stats)
{
    int bc = blockIdx.x;
    int R = rows_len[bc], L = cols_len[bc];
    const float* xp = x + (size_t)bc * AW;
    int n = R * L;
    float sx = 0.f, sxx = 0.f;
    for (int i = threadIdx.x; i < n; i += 256) {
        int a = i / L, w = i - a * L;
        float v = xp[a * NW + w];
        sx += v;
        sxx = fmaf(v, v, sxx);
    }
    __shared__ float r1[256], r2[256];
    r1[threadIdx.x] = sx; r2[threadIdx.x] = sxx;
    __syncthreads();
    for (int s = 128; s > 0; s >>= 1) {
        if (threadIdx.x < s) {
            r1[threadIdx.x] += r1[threadIdx.x + s];
            r2[threadIdx.x] += r2[threadIdx.x + s];
        }
        __syncthreads();
    }
    if (threadIdx.x == 0) {
        float fn = (float)n;
        float mean = r1[0] / fn;
        float var = fmaxf((r2[0] - r1[0] * r1[0] / fn) / (fn - 1.f), 0.f);
        float sd = fmaxf(sqrtf(var), 1e-12f);
        stats[2 * bc] = mean;
        stats[2 * bc + 1] = 1.f / sd;
    }
}

// ---------------------------------------------------------------- prep: transpose first 24 rows of each stack's W1
__global__ __launch_bounds__(256) void prep_kernel(
    const float* __restrict__ tw1, float* __restrict__ w1t)
{
    int i = blockIdx.x * 256 + threadIdx.x;     // [s][j][t]
    if (i >= 4 * NHID * 24) return;
    int s = i / (NHID * 24), r = i % (NHID * 24);
    int j = r / 24, t = r % 24;
    w1t[i] = tw1[(size_t)s * 64 * NHID + t * NHID + j];
}

// ---------------------------------------------------------------- t0 MLP (1->128->32), 4 elem/thread
__global__ __launch_bounds__(256, 2) void t0_kernel(
    const float* __restrict__ x, const int* __restrict__ rows_len,
    const int* __restrict__ cols_len, const float* __restrict__ stats,
    const float* __restrict__ w1, const float* __restrict__ b1,
    const float* __restrict__ w2, const float* __restrict__ b2,
    float* __restrict__ h)
{
    int tid = threadIdx.x;
    int bc = blockIdx.x / 9;
    int base = (blockIdx.x % 9) * 1024;
    int R = rows_len[bc], L = cols_len[bc];
    float mean = stats[2 * bc], rstd = stats[2 * bc + 1];

    int e0 = base + tid;
    float xv[4], mk[4];
    #pragma unroll
    for (int r = 0; r < 4; r++) {
        int e = e0 + 256 * r;
        int a = e / NW, w = e - a * NW;
        bool v = (a < R) && (w < L);
        mk[r] = v ? 1.f : 0.f;
        xv[r] = v ? (x[(size_t)bc * AW + e] - mean) * rstd : 0.f;
    }

    float o[4][NF];
    #pragma unroll
    for (int f = 0; f < NF; f++) {
        float bb = b2[f];
        #pragma unroll
        for (int r = 0; r < 4; r++) o[r][f] = bb;
    }
    for (int j = 0; j < NHID; j++) {
        float wj = w1[j], bj = b1[j];
        float hv[4];
        #pragma unroll
        for (int r = 0; r < 4; r++) hv[r] = fmaxf(fmaf(xv[r], wj, bj), 0.f);
        const float* wr = &w2[j * NF];
        #pragma unroll
        for (int f = 0; f < NF; f++) {
            float q = wr[f];
            #pragma unroll
            for (int r = 0; r < 4; r++) o[r][f] = fmaf(hv[r], q, o[r][f]);
        }
    }
    float* hp = h + (size_t)bc * NF * AW;
    #pragma unroll
    for (int f = 0; f < NF; f++) {
        #pragma unroll
        for (int r = 0; r < 4; r++)
            hp[(size_t)f * AW + e0 + 256 * r] = o[r][f] * mk[r];
    }
}

// ---------------------------------------------------------------- pools: one block per (bc,f) plane, single read pass
__global__ __launch_bounds__(256) void pool_kernel(
    const float* __restrict__ h, float* __restrict__ rowsum,
    float* __restrict__ colsum, float* __restrict__ matsum,
    float* __restrict__ cmax)
{
    __shared__ float smax[4];
    __shared__ float ssum[4];
    __shared__ float scol[4][96];
    int blk = blockIdx.x;            // bc*32 + f
    int bc = blk >> 5, f = blk & 31;
    const float* p = h + (size_t)blk * AW;
    int tid = threadIdx.x;
    int lane = tid & 63, wv = tid >> 6;
    int mode = f & 3, k = f >> 2;

    float lmax = -FLT_MAX;
    if (mode == 0) {
        for (int i = tid; i < AW; i += 256) lmax = fmaxf(lmax, p[i]);
    } else if (mode == 1) {
        // per-row sin-sums; max folded into same read
        for (int r = 0; r < 24; r++) {
            int a = wv + 4 * r;
            float v0 = p[a * NW + lane];
            lmax = fmaxf(lmax, v0);
            float s = sinf(v0);
            if (lane < 32) {
                float v1 = p[a * NW + 64 + lane];
                lmax = fmaxf(lmax, v1);
                s += sinf(v1);
            }
            #pragma unroll
            for (int off = 32; off >= 1; off >>= 1) s += __shfl_xor(s, off, 64);
            if (lane == 0) rowsum[(bc * NA + a) * 8 + k] = s;
        }
    } else if (mode == 2) {
        float acc0 = 0.f, acc1 = 0.f;
        for (int r = 0; r < 24; r++) {
            int a = wv + 4 * r;
            float v0 = p[a * NW + lane];
            lmax = fmaxf(lmax, v0);
            acc0 += sinf(v0);
            if (lane < 32) {
                float v1 = p[a * NW + 64 + lane];
                lmax = fmaxf(lmax, v1);
                acc1 += sinf(v1);
            }
        }
        scol[wv][lane] = acc0;
        if (lane < 32) scol[wv][64 + lane] = acc1;
    } else {
        float s = 0.f;
        for (int i = tid; i < AW; i += 256) {
            float v = p[i];
            lmax = fmaxf(lmax, v);
            s += sinf(v);
        }
        #pragma unroll
        for (int off = 32; off >= 1; off >>= 1) s += __shfl_xor(s, off, 64);
        if (lane == 0) ssum[wv] = s;
    }
    #pragma unroll
    for (int off = 32; off >= 1; off >>= 1) lmax = fmaxf(lmax, __shfl_xor(lmax, off, 64));
    if (lane == 0) smax[wv] = lmax;
    __syncthreads();
    if (tid == 0)
        cmax[bc * NF + f] = fmaxf(fmaxf(smax[0], smax[1]), fmaxf(smax[2], smax[3]));
    if (mode == 2 && tid < 96)
        colsum[(bc * NW + tid) * 8 + k] =
            scol[0][tid] + scol[1][tid] + scol[2][tid] + scol[3][tid];
    if (mode == 3 && tid == 0)
        matsum[bc * 8 + k] = ssum[0] + ssum[1] + ssum[2] + ssum[3];
}

// ---------------------------------------------------------------- stack MLP: SGPR weights, 4 elem/thread
__global__ __launch_bounds__(256, 2) void mlp_kernel(
    float* __restrict__ h, const float* __restrict__ rowsum,
    const float* __restrict__ colsum, const float* __restrict__ matsum,
    const float* __restrict__ cmax, const int* __restrict__ rows_len,
    const int* __restrict__ cols_len, const float* __restrict__ w1t,
    const float* __restrict__ w1, const float* __restrict__ b1,
    const float* __restrict__ w2, const float* __restrict__ b2)
{
    __shared__ float sconst[NHID];
    __shared__ float sbm[NF];
    int tid = threadIdx.x;
    int bc = blockIdx.x / 9;
    int b = bc / NC;

    if (tid >= 224) {   // 32 threads: per-batch max over C
        int f = tid - 224;
        float m = cmax[(b * NC) * NF + f];
        for (int c = 1; c < NC; c++) m = fmaxf(m, cmax[(b * NC + c) * NF + f]);
        sbm[f] = m;
    }
    __syncthreads();
    if (tid < NHID) {   // fold b1 + e3 (matsum) + h1 (batch max) into per-block const
        int j = tid;
        float v = b1[j];
        const float* mp = matsum + bc * 8;
        #pragma unroll
        for (int k = 0; k < 8; k++) v = fmaf(mp[k], w1[(24 + k) * NHID + j], v);
        #pragma unroll
        for (int f = 0; f < NF; f++) v = fmaf(sbm[f], w1[(32 + f) * NHID + j], v);
        sconst[j] = v;
    }
    __syncthreads();

    int R = rows_len[bc], L = cols_len[bc];
    int base = (blockIdx.x % 9) * 1024;
    int e0 = base + tid;
    float* hp = h + (size_t)bc * NF * AW;

    float p[4][24], mk[4];
    #pragma unroll
    for (int r = 0; r < 4; r++) {
        int e = e0 + 256 * r;
        int a = e / NW, w = e - a * NW;
        mk[r] = (a < R && w < L) ? 1.f : 0.f;
        #pragma unroll
        for (int k = 0; k < 8; k++)
            p[r][k] = sinf(hp[(size_t)(4 * k) * AW + e]);   // e0: masked h==0 -> sin 0
        const float4* rp = (const float4*)(rowsum + (bc * NA + a) * 8);
        float4 r0 = rp[0], r1 = rp[1];
        p[r][8] = r0.x;  p[r][9] = r0.y;  p[r][10] = r0.z; p[r][11] = r0.w;
        p[r][12] = r1.x; p[r][13] = r1.y; p[r][14] = r1.z; p[r][15] = r1.w;
        const float4* cp = (const float4*)(colsum + (bc * NW + w) * 8);
        float4 c0 = cp[0], c1 = cp[1];
        p[r][16] = c0.x; p[r][17] = c0.y; p[r][18] = c0.z; p[r][19] = c0.w;
        p[r][20] = c1.x; p[r][21] = c1.y; p[r][22] = c1.z; p[r][23] = c1.w;
    }

    float o[4][NF];
    #pragma unroll
    for (int f = 0; f < NF; f++) {
        float bb = b2[f];
        #pragma unroll
        for (int r = 0; r < 4; r++) o[r][f] = bb;
    }

    for (int j = 0; j < NHID; j++) {
        const float* w1r = w1t + j * 24;   // uniform -> s_load
        float sc = sconst[j];
        float v[4] = {sc, sc, sc, sc};
        #pragma unroll
        for (int t = 0; t < 24; t++) {
            float q = w1r[t];
            #pragma unroll
            for (int r = 0; r < 4; r++) v[r] = fmaf(p[r][t], q, v[r]);
        }
        #pragma unroll
        for (int r = 0; r < 4; r++) v[r] = fmaxf(v[r], 0.f);
        const float* w2r = w2 + j * NF;    // uniform -> s_load
        #pragma unroll
        for (int f = 0; f < NF; f++) {
            float q = w2r[f];
            #pragma unroll
            for (int r = 0; r < 4; r++) o[r][f] = fmaf(v[r], q, o[r][f]);
        }
    }
    #pragma unroll
    for (int f = 0; f < NF; f++) {
        float* addr = hp + (size_t)f * AW;
        #pragma unroll
        for (int r = 0; r < 4; r++) {
            int e = e0 + 256 * r;
            float old = addr[e];
            addr[e] = (old + o[r][f]) * mk[r];
        }
    }
}

// ---------------------------------------------------------------- RMS over (a,w)
__global__ __launch_bounds__(256) void rms_kernel(
    const float* __restrict__ h, const int* __restrict__ rows_len,
    const int* __restrict__ cols_len, float* __restrict__ rms)
{
    int bc = blockIdx.x;
    int f = threadIdx.x >> 3, g = threadIdx.x & 7;
    const float* p = h + ((size_t)bc * NF + f) * AW;
    float s = 0.f;
    for (int i = g; i < AW; i += 8) { float v = p[i]; s = fmaf(v, v, s); }
    __shared__ float red[NF][9];
    red[f][g] = s;
    __syncthreads();
    if (threadIdx.x < NF) {
        float t = 0.f;
        #pragma unroll
        for (int g2 = 0; g2 < 8; g2++) t += red[threadIdx.x][g2];
        float n = (float)(rows_len[bc] * cols_len[bc]);
        t = fmaxf(t, 1e-20f);
        rms[bc * NF + threadIdx.x] = sqrtf(t / fmaxf(n, 1e-12f));
    }
}

// ---------------------------------------------------------------- final mean-over-C + MLP + tanh
__global__ __launch_bounds__(64) void out_kernel(
    const float* __restrict__ rms, const float* __restrict__ w1,
    const float* __restrict__ b1, const float* __restrict__ w2,
    const float* __restrict__ b2, float* __restrict__ out)
{
    int b = threadIdx.x;
    if (b >= NB) return;
    float hm[NF];
    #pragma unroll
    for (int f = 0; f < NF; f++) {
        float s = 0.f;
        for (int c = 0; c < NC; c++) s += rms[(b * NC + c) * NF + f];
        hm[f] = s / (float)NC;
    }
    float o0 = b2[0], o1 = b2[1];
    for (int j = 0; j < NHID; j++) {
        float v = b1[j];
        #pragma unroll
        for (int f = 0; f < NF; f++) v = fmaf(hm[f], w1[f * NHID + j], v);
        v = fmaxf(v, 0.f);
        o0 = fmaf(v, w2[j * 2 + 0], o0);
        o1 = fmaf(v, w2[j * 2 + 1], o1);
    }
    out[b * 2 + 0] = 8.f * tanhf(o0);
    out[b * 2 + 1] = 8.f * tanhf(o1);
}

// ---------------------------------------------------------------- launcher
extern "C" void kernel_launch(void* const* d_in, const int* in_sizes, int n_in,
                              void* d_out, int out_size, void* d_ws, size_t ws_size,
                              hipStream_t stream)
{
    const float* x    = (const float*)d_in[0];
    const int* rl     = (const int*)d_in[1];
    const int* cl     = (const int*)d_in[2];
    const float* t0w1 = (const float*)d_in[3];
    const float* t0b1 = (const float*)d_in[4];
    const float* t0w2 = (const float*)d_in[5];
    const float* t0b2 = (const float*)d_in[6];
    const float* tw1  = (const float*)d_in[7];
    const float* tb1  = (const float*)d_in[8];
    const float* tw2  = (const float*)d_in[9];
    const float* tb2  = (const float*)d_in[10];
    const float* ow1  = (const float*)d_in[11];
    const float* ob1  = (const float*)d_in[12];
    const float* ow2  = (const float*)d_in[13];
    const float* ob2  = (const float*)d_in[14];
    float* out = (float*)d_out;

    // R1-proven workspace layout
    float* ws    = (float*)d_ws;
    float* h     = ws;                               // NEL*NF  (planar [bc][f][a*96+w])
    float* stats = h + NEL * NF;                     // 2*NBC
    float* rowb  = stats + 2 * NBC;                  // NBC*NA*8
    float* colb  = rowb + (size_t)NBC * NA * 8;      // NBC*NW*8
    float* matb  = colb + (size_t)NBC * NW * 8;      // NBC*8
    float* cmxb  = matb + NBC * 8;                   // NBC*NF
    float* rmsb  = cmxb + NBC * NF;                  // NBC*NF
    float* w1tb  = rmsb + NBC * NF;                  // 4*NHID*24

    stats_kernel<<<NBC, 256, 0, stream>>>(x, rl, cl, stats);
    prep_kernel<<<(4 * NHID * 24 + 255) / 256, 256, 0, stream>>>(tw1, w1tb);
    t0_kernel<<<NBC * 9, 256, 0, stream>>>(x, rl, cl, stats,
                                           t0w1, t0b1, t0w2, t0b2, h);
    for (int s = 0; s < 4; s++) {
        pool_kernel<<<NBC * NF, 256, 0, stream>>>(h, rowb, colb, matb, cmxb);
        mlp_kernel<<<NBC * 9, 256, 0, stream>>>(h, rowb, colb, matb, cmxb, rl, cl,
            w1tb + (size_t)s * NHID * 24,
            tw1 + (size_t)s * 64 * NHID, tb1 + s * NHID,
            tw2 + (size_t)s * NHID * NF, tb2 + s * NF);
    }
    rms_kernel<<<NBC, 256, 0, stream>>>(h, rl, cl, rmsb);
    out_kernel<<<1, 64, 0, stream>>>(rmsb, ow1, ob1, ow2, ob2, out);
}